// Round 19
// baseline (215.953 us; speedup 1.0000x reference)
//
#include <hip/hip_runtime.h>
#include <hip/hip_bf16.h>
#include <math.h>

#define B_ 2
#define L_ 2048
#define DM_ 1024
#define DC_ 512
#define NH_ 8
#define DH_ 64
#define MR_ (B_*L_)   // 4096 rows
#define BH_ (B_*NH_)  // 16

typedef unsigned short u16;
typedef unsigned int u32;
typedef __attribute__((ext_vector_type(8))) short bf16x8;
typedef __attribute__((ext_vector_type(4))) float f32x4;

static __device__ __forceinline__ u16 f2bf(float x) {
  union { float f; u32 u; } v; v.f = x;
  u32 r = (v.u + 0x7fffu + ((v.u >> 16) & 1u)) >> 16;  // RNE
  return (u16)r;
}
static __device__ __forceinline__ float bf2f(u16 x) {
  union { u32 u; float f; } v; v.u = ((u32)x) << 16;
  return v.f;
}
// fast 2^x (single v_exp_f32); guarded fallback keeps compile safe
static __device__ __forceinline__ float fexp2(float x) {
#if __has_builtin(__builtin_amdgcn_exp2f)
  return __builtin_amdgcn_exp2f(x);
#else
  return __expf(x * 0.69314718056f);
#endif
}
#define LOG2E 1.44269504089f
#define C2    0.18033688011f   /* 0.125 * log2(e) */

// Direct global->LDS DMA, 16B per lane (1KB per wave instruction).
static __device__ __forceinline__ void gld16(const u16* g, u16* l) {
  __builtin_amdgcn_global_load_lds(
      (const __attribute__((address_space(1))) u32*)g,
      (__attribute__((address_space(3))) u32*)l, 16, 0, 0);
}

// ---------------------------------------------------------------------------
// One-shot fp32 -> bf16 conversion: x1, Wq, Wk, Wst, Wout.
// ---------------------------------------------------------------------------
__global__ __launch_bounds__(256) void cvt_k(
    const float* __restrict__ src,
    const float* __restrict__ Wq, const float* __restrict__ Wk,
    const float* __restrict__ Wst, const float* __restrict__ Wout,
    u16* __restrict__ x1b, u16* __restrict__ Wqb, u16* __restrict__ Wkb,
    u16* __restrict__ Wstb, u16* __restrict__ Woutb)
{
  int v = blockIdx.x * 256 + threadIdx.x;
  if (v < 524288) {
    const int m = v >> 7, c = (v & 127) << 2;
    float4 f = *(const float4*)(src + (size_t)m * DM_ + c);
    *(ushort4*)(x1b + (size_t)m * DC_ + c) =
        make_ushort4(f2bf(f.x), f2bf(f.y), f2bf(f.z), f2bf(f.w));
    return;
  }
  v -= 524288;
  const float* sp; u16* dp;
  if (v < 65536)       { sp = Wq;   dp = Wqb; }
  else if (v < 131072) { sp = Wk;   dp = Wkb;   v -= 65536; }
  else if (v < 196608) { sp = Wst;  dp = Wstb;  v -= 131072; }
  else                 { sp = Wout; dp = Woutb; v -= 196608; }
  float4 f = *(const float4*)(sp + (size_t)v * 4);
  *(ushort4*)(dp + (size_t)v * 4) =
      make_ushort4(f2bf(f.x), f2bf(f.y), f2bf(f.z), f2bf(f.w));
}

// ---------------------------------------------------------------------------
// MERGED frag + conv kernel (unchanged).
// ---------------------------------------------------------------------------
__global__ __launch_bounds__(256) void fc_k(
    const u16* __restrict__ Kh, u16* __restrict__ Kf, u16* __restrict__ Gf,
    const u16* __restrict__ x1b, const float* __restrict__ cw,
    const float* __restrict__ cb, float* __restrict__ sal)
{
  __shared__ float smem[5576];
  const int tid = threadIdx.x;
  if (blockIdx.x < 512) {
    u16* T = (u16*)smem;
    const int bh = blockIdx.x >> 5, mblk = blockIdx.x & 31;
    const int m0 = mblk << 6;
    const u16* Kb = Kh + ((size_t)bh * L_ + m0) * DH_;
    {
      const int r = tid >> 2, c = (tid & 3) << 4;
      *(bf16x8*)&T[r*72 + c]     = *(const bf16x8*)(Kb + (size_t)r * DH_ + c);
      *(bf16x8*)&T[r*72 + c + 8] = *(const bf16x8*)(Kb + (size_t)r * DH_ + c + 8);
    }
    __syncthreads();
#pragma unroll
    for (int i = 0; i < 2; ++i) {
      const int s = tid + (i << 8);
      const int mt_l = s >> 7, ks = (s >> 6) & 1, lane = s & 63;
      const int lr = lane & 15, lg = lane >> 4;
      bf16x8 v = *(bf16x8*)&T[(mt_l*16 + lr)*72 + ks*32 + lg*8];
      *(bf16x8*)(Kf + ((size_t)((bh*128 + mblk*4 + mt_l)*2 + ks)*64 + lane)*8) = v;
    }
#pragma unroll
    for (int i = 0; i < 2; ++i) {
      const int s = tid + (i << 8);
      const int ds = s >> 7, ks = (s >> 6) & 1, lane = s & 63;
      const int lr = lane & 15, lg = lane >> 4;
      bf16x8 v;
#pragma unroll
      for (int j = 0; j < 8; ++j)
        v[j] = (short)T[(ks*32 + lg*8 + j)*72 + ds*16 + lr];
      *(bf16x8*)(Gf + ((size_t)(((bh*4 + ds)*32 + mblk)*2 + ks)*64 + lane)*8) = v;
    }
  } else {
    float* xs = smem;
    float* part = smem + 5320;
    const int id = blockIdx.x - 512;
    const int b = id >> 8;
    const int l0 = (id & 255) << 3;
    const int li = tid >> 5;
    const int h  = (tid >> 2) & 7;
    const int cq = tid & 3;
    for (int t = tid; t < 10*128; t += 256) {
      const int r = t >> 7, c4 = (t & 127) << 2;
      const int l = l0 - 1 + r;
      float4 v = make_float4(0.f, 0.f, 0.f, 0.f);
      if (l >= 0 && l < L_) {
        ushort4 u = *(const ushort4*)(x1b + (size_t)(b*L_ + l) * DC_ + c4);
        v = make_float4(bf2f(u.x), bf2f(u.y), bf2f(u.z), bf2f(u.w));
      }
      *(float4*)&xs[r*532 + c4 + (c4 >> 5)] = v;
    }
    __syncthreads();
    float acc = 0.f;
    const int cbase = cq << 7;
#pragma unroll 4
    for (int c = 0; c < 128; ++c) {
      const int cc = cbase + c;
      const int col = cc + (cc >> 5);
      const float* w = cw + ((size_t)h * DC_ + cc) * 3;
      acc += xs[(li+0)*532 + col]*w[0] + xs[(li+1)*532 + col]*w[1]
           + xs[(li+2)*532 + col]*w[2];
    }
    part[(li*8 + h)*4 + cq] = acc;
    __syncthreads();
    if (tid < 64) {
      const int l2 = tid >> 3, h2 = tid & 7;
      const float s = cb[h2] + part[(l2*8 + h2)*4 + 0] + part[(l2*8 + h2)*4 + 1]
                             + part[(l2*8 + h2)*4 + 2] + part[(l2*8 + h2)*4 + 3];
      sal[(size_t)(b*NH_ + h2) * L_ + l0 + l2] = s;
    }
  }
}

// ---------------------------------------------------------------------------
// bf16 MFMA GEMM v2 (r18, gld16 staging — unchanged).
// ---------------------------------------------------------------------------
template<int MODE, int BN>
__global__ __launch_bounds__(256) void mgemm_k(
    const u16* __restrict__ A, const u16* __restrict__ A2,
    const u16* __restrict__ W, const float* __restrict__ bias,
    const float* __restrict__ src, u16* __restrict__ Ob,
    float* __restrict__ Of, int Ndim, int Kdim)
{
  constexpr int MF = (BN == 128) ? 4 : 2;
  constexpr int WC = BN / 64;
  __shared__ u16 As[128 * 32];
  __shared__ u16 Ws[BN * 32];
  const int tid = threadIdx.x;
  const int wid = tid >> 6, lane = tid & 63;
  const int lr = lane & 15, lg = lane >> 4;
  const int wr = wid / WC, wc = wid % WC;
  const int m0 = blockIdx.y << 7;
  const int n0 = blockIdx.x * BN;
  const int lrow = lane >> 2;
  const int lcol = (lane & 3) << 3;

  f32x4 acc[MF][4];
#pragma unroll
  for (int mi = 0; mi < MF; ++mi)
#pragma unroll
    for (int ni = 0; ni < 4; ++ni)
      acc[mi][ni] = (f32x4){0.f, 0.f, 0.f, 0.f};

  for (int k0 = 0; k0 < Kdim; k0 += 32) {
#pragma unroll
    for (int c = 0; c < 2; ++c) {
      const int ch = wid + c*4;
      const int row = ch*16 + lrow;
      const u16* ap;
      if (MODE == 2)
        ap = (k0 < 512) ? A  + (size_t)(m0 + row) * 512 + k0 + lcol
                        : A2 + (size_t)(m0 + row) * 512 + (k0 - 512) + lcol;
      else
        ap = A + (size_t)(m0 + row) * Kdim + k0 + lcol;
      gld16(ap, &As[ch*512]);
    }
    if (BN == 128) {
#pragma unroll
      for (int c = 0; c < 2; ++c) {
        const int ch = wid + c*4;
        const int row = ch*16 + lrow;
        gld16(W + (size_t)(n0 + row) * Kdim + k0 + lcol, &Ws[ch*512]);
      }
    } else {
      const int row = wid*16 + lrow;
      gld16(W + (size_t)(n0 + row) * Kdim + k0 + lcol, &Ws[wid*512]);
    }
    __syncthreads();
    bf16x8 af[MF], bfr[4];
#pragma unroll
    for (int mi = 0; mi < MF; ++mi)
      af[mi] = *(bf16x8*)&As[(wr * (MF * 16) + mi * 16 + lr) * 32 + lg * 8];
#pragma unroll
    for (int ni = 0; ni < 4; ++ni)
      bfr[ni] = *(bf16x8*)&Ws[(wc * 64 + ni * 16 + lr) * 32 + lg * 8];
#pragma unroll
    for (int mi = 0; mi < MF; ++mi)
#pragma unroll
      for (int ni = 0; ni < 4; ++ni)
        acc[mi][ni] = __builtin_amdgcn_mfma_f32_16x16x32_bf16(
            af[mi], bfr[ni], acc[mi][ni], 0, 0, 0);
    __syncthreads();
  }

#pragma unroll
  for (int mi = 0; mi < MF; ++mi)
#pragma unroll
    for (int ni = 0; ni < 4; ++ni)
#pragma unroll
      for (int r = 0; r < 4; ++r) {
        const int m = m0 + wr * (MF * 16) + mi * 16 + lg * 4 + r;
        const int n = n0 + wc * 64 + ni * 16 + lr;
        if (MODE == 0) {
          const float v = acc[mi][ni][r] + bias[n];
          const int b = m >> 11, l = m & (L_ - 1), h = n >> 6, d = n & (DH_ - 1);
          Ob[((size_t)(b * NH_ + h) * L_ + l) * DH_ + d] = f2bf(v);
        } else if (MODE == 1) {
          const float v = acc[mi][ni][r] + bias[n];
          const float x2 = src[(size_t)m * DM_ + DC_ + n];
          const float s = 1.f / (1.f + __expf(-v));
          Ob[(size_t)m * DC_ + n] = f2bf(s * tanhf(x2) + (1.f - s) * x2);
        } else if (MODE == 2) {
          const float v = acc[mi][ni][r] + bias[n];
          Of[(size_t)m * Ndim + n] = v;
        } else {
          const float bb = (n < 512) ? bias[n] : src[n - 512];
          const float v = acc[mi][ni][r] + bb;
          const int b = m >> 11, l = m & (L_ - 1);
          const int h16 = n >> 6, d = n & (DH_ - 1);
          u16* dst = (h16 < 8) ? Ob : (u16*)Of;
          dst[((size_t)(b * NH_ + (h16 & 7)) * L_ + l) * DH_ + d] = f2bf(v);
        }
      }
}

// ---------------------------------------------------------------------------
// MFMA attention v11: SINGLE sweep. Block = 16 q-rows, 4 waves; wave wm owns
// key-quarter [wm*512, +512) = 8 tiles. Per tile: QK (swapped) -> exp2 ->
// {rsum, Ps(LDS), Pc bf16 reg-cache} -> PV partial. Then cross-wave rowsum
// combine (1 barrier), PV tree combine (3 barriers), and a lean store loop
// from Pc * inv (no QK recompute, no exp recompute, no Kf re-reads).
// Pc = 8x4 ushort4 = 64 VGPR, fully static indexing (full unroll).
// ---------------------------------------------------------------------------
__global__ __launch_bounds__(256) void attn_k(
    const u16* __restrict__ Qh, const u16* __restrict__ Kf,
    const u16* __restrict__ Gf, const float* __restrict__ sal,
    float* __restrict__ attn, u16* __restrict__ ctxb)
{
  __shared__ u16 Ps[4*16*72];        // [wave][q=16][64+8] bf16
  __shared__ float sal_s[L_];        // pre-scaled by log2e
  __shared__ float RsB[4][16];
  __shared__ float PvB[2][16*64];

  const int tid = threadIdx.x;
  const int wm = tid >> 6, lane = tid & 63;
  const int lr = lane & 15, lg = lane >> 4;
  const int lin = blockIdx.x;
  const int swz = (lin & 7) * 256 + (lin >> 3); // XCD-bijective (2048 = 8*256)
  const int bh = swz >> 7, q0 = (swz & 127) << 4;

  const u16* Kfb = Kf + (size_t)bh * 131072;
  const u16* Gfb = Gf + (size_t)bh * 131072;

  {
    const float4* sp = (const float4*)(sal + (size_t)bh * L_);
    float4* dp = (float4*)sal_s;
#pragma unroll
    for (int i = 0; i < 2; ++i) {
      float4 v = sp[tid + i*256];
      v.x *= LOG2E; v.y *= LOG2E; v.z *= LOG2E; v.w *= LOG2E;
      dp[tid + i*256] = v;
    }
  }
  // Q frags: all 4 waves share the same 16 q-rows
  const u16* Qp = Qh + ((size_t)bh * L_ + q0) * DH_;
  bf16x8 qf[2];
  qf[0] = *(const bf16x8*)(Qp + (size_t)lr * DH_ + lg*8);
  qf[1] = *(const bf16x8*)(Qp + (size_t)lr * DH_ + 32 + lg*8);
  __syncthreads();  // sal_s

  // ============ single sweep over this wave's 8 tiles ============
  float rsum = 0.f;
  f32x4 pvacc[4] = {{0.f,0.f,0.f,0.f},{0.f,0.f,0.f,0.f},
                    {0.f,0.f,0.f,0.f},{0.f,0.f,0.f,0.f}};
  ushort4 Pc[8][4];                  // bf16 P cache: 64 VGPR, static idx
  u16* PsW = &Ps[wm*16*72];
#pragma unroll
  for (int t = 0; t < 8; ++t) {
    const int tt = wm*8 + t;
    const int m0 = tt << 6;
    bf16x8 g[8];
#pragma unroll
    for (int f = 0; f < 8; ++f)
      g[f] = *(const bf16x8*)(Gfb + ((size_t)(((f>>1)*32 + tt)*2 + (f&1))*64 + lane)*8);
#pragma unroll
    for (int ms = 0; ms < 4; ++ms) {
      bf16x8 k0 = *(const bf16x8*)(Kfb + ((size_t)((tt*4 + ms)*2 + 0)*64 + lane)*8);
      bf16x8 k1 = *(const bf16x8*)(Kfb + ((size_t)((tt*4 + ms)*2 + 1)*64 + lane)*8);
      f32x4 acc = {0.f, 0.f, 0.f, 0.f};
      acc = __builtin_amdgcn_mfma_f32_16x16x32_bf16(k0, qf[0], acc, 0, 0, 0);
      acc = __builtin_amdgcn_mfma_f32_16x16x32_bf16(k1, qf[1], acc, 0, 0, 0);
      // lane: q = lr, m = m0 + ms*16 + lg*4 + r
      float4 sl = *(const float4*)&sal_s[m0 + ms*16 + lg*4];
      float p0 = fexp2(fmaf(acc[0], C2, sl.x));
      float p1 = fexp2(fmaf(acc[1], C2, sl.y));
      float p2 = fexp2(fmaf(acc[2], C2, sl.z));
      float p3 = fexp2(fmaf(acc[3], C2, sl.w));
      rsum += (p0 + p1) + (p2 + p3);
      ushort4 pw = make_ushort4(f2bf(p0), f2bf(p1), f2bf(p2), f2bf(p3));
      Pc[t][ms] = pw;
      *(ushort4*)&PsW[lr*72 + ms*16 + lg*4] = pw;
    }
    // PV partial: pvacc += P @ K
#pragma unroll
    for (int ks = 0; ks < 2; ++ks) {
      bf16x8 pa = *(bf16x8*)&PsW[lr*72 + ks*32 + lg*8];
#pragma unroll
      for (int ds = 0; ds < 4; ++ds)
        pvacc[ds] = __builtin_amdgcn_mfma_f32_16x16x32_bf16(pa, g[ds*2+ks], pvacc[ds], 0, 0, 0);
    }
  }

  // ============ rowsum: intra-wave + cross-wave combine ============
  rsum += __shfl_xor(rsum, 16);
  rsum += __shfl_xor(rsum, 32);      // rsum = this wave's partial for q = lr
  if (lane < 16) RsB[wm][lane] = rsum;
  __syncthreads();
  const float inv = 1.0f / (RsB[0][lr] + RsB[1][lr] + RsB[2][lr] + RsB[3][lr]);

  // ============ PV tree combine across waves ============
  if (wm & 1) {
    float* d = &PvB[wm >> 1][0];
#pragma unroll
    for (int ds = 0; ds < 4; ++ds)
#pragma unroll
      for (int r = 0; r < 4; ++r)
        d[(lg*4 + r)*64 + ds*16 + lr] = pvacc[ds][r];
  }
  __syncthreads();
  if (!(wm & 1)) {
    const float* s = &PvB[wm >> 1][0];
#pragma unroll
    for (int ds = 0; ds < 4; ++ds)
#pragma unroll
      for (int r = 0; r < 4; ++r)
        pvacc[ds][r] += s[(lg*4 + r)*64 + ds*16 + lr];
  }
  __syncthreads();
  if (wm == 2) {
    float* d = &PvB[0][0];
#pragma unroll
    for (int ds = 0; ds < 4; ++ds)
#pragma unroll
      for (int r = 0; r < 4; ++r)
        d[(lg*4 + r)*64 + ds*16 + lr] = pvacc[ds][r];
  }
  __syncthreads();
  if (wm == 0) {
    const float* s = &PvB[0][0];
    const int b = bh >> 3, h = bh & 7;
    float invq[4];
#pragma unroll
    for (int r = 0; r < 4; ++r) invq[r] = __shfl(inv, lg*4 + r);
#pragma unroll
    for (int ds = 0; ds < 4; ++ds)
#pragma unroll
      for (int r = 0; r < 4; ++r) {
        const float v = pvacc[ds][r] + s[(lg*4 + r)*64 + ds*16 + lr];
        ctxb[((size_t)(b*L_ + q0 + lg*4 + r)) * DC_ + h*DH_ + ds*16 + lr] =
            f2bf(v * invq[r]);
      }
  }

  // ============ attn store from reg cache (no recompute) ============
  float* arow = attn + ((size_t)bh * L_ + q0 + lr) * L_ + wm*512;
#pragma unroll
  for (int t = 0; t < 8; ++t)
#pragma unroll
    for (int ms = 0; ms < 4; ++ms) {
      const ushort4 pw = Pc[t][ms];
      f32x4 o;
      o[0] = bf2f(pw.x) * inv;
      o[1] = bf2f(pw.y) * inv;
      o[2] = bf2f(pw.z) * inv;
      o[3] = bf2f(pw.w) * inv;
      *(f32x4*)(arow + t*64 + ms*16 + lg*4) = o;
    }
}

// ---------------------------------------------------------------------------
extern "C" void kernel_launch(void* const* d_in, const int* in_sizes, int n_in,
                              void* d_out, int out_size, void* d_ws, size_t ws_size,
                              hipStream_t stream)
{
  const float* src   = (const float*)d_in[0];
  const float* Wq    = (const float*)d_in[1];
  const float* bq    = (const float*)d_in[2];
  const float* Wk    = (const float*)d_in[3];
  const float* bk    = (const float*)d_in[4];
  const float* convw = (const float*)d_in[5];
  const float* convb = (const float*)d_in[6];
  const float* Wst   = (const float*)d_in[7];
  const float* bst   = (const float*)d_in[8];
  const float* Wout  = (const float*)d_in[9];
  const float* bout  = (const float*)d_in[10];

  float* out  = (float*)d_out;                 // fp32
  float* attn = out + (size_t)MR_ * DM_;

  u16*   x1b   = (u16*)d_ws;                    // [4096][512]
  u16*   Kh    = x1b   + (size_t)MR_ * DC_;     // K heads; becomes Kf in place
  u16*   Qh    = Kh    + (size_t)BH_ * L_ * DH_;
  u16*   Gf    = Qh    + (size_t)BH_ * L_ * DH_;// [16][4][32][2][64][8]
  u16*   ctxb  = Gf    + (size_t)BH_ * L_ * DH_;// [4096][512]
  u16*   y2b   = ctxb  + (size_t)MR_ * DC_;     // [4096][512]
  u16*   Wqb   = y2b   + (size_t)MR_ * DC_;     // [512][512]  (Wqb||Wkb stacked)
  u16*   Wkb   = Wqb   + (size_t)DC_ * DC_;
  u16*   Wstb  = Wkb   + (size_t)DC_ * DC_;
  u16*   Woutb = Wstb  + (size_t)DC_ * DC_;     // [1024][1024]
  float* salb  = (float*)(Woutb + (size_t)DM_ * DM_); // [16][2048]

  (void)in_sizes; (void)n_in; (void)out_size; (void)ws_size;

  cvt_k<<<dim3(3840), 256, 0, stream>>>(src, Wq, Wk, Wst, Wout,
                                        x1b, Wqb, Wkb, Wstb, Woutb);
  // fused Q+K projection: W = [Wqb ; Wkb] stacked, one launch
  mgemm_k<3,64><<<dim3(16, 32), 256, 0, stream>>>(
      x1b, nullptr, Wqb, bq, bk, Qh, (float*)Kh, DM_, DC_);
  // merged: fragmentize K (blocks 0..511) + saliency conv (blocks 512..1023)
  fc_k<<<dim3(1024), 256, 0, stream>>>(Kh, Kh /*in-place Kf*/, Gf,
                                       x1b, convw, convb, salb);
  // single-sweep attention with P register cache
  attn_k<<<dim3(2048), 256, 0, stream>>>(Qh, Kh /*Kf*/, Gf, salb, attn, ctxb);
  mgemm_k<1,64><<<dim3(8, 32), 256, 0, stream>>>(ctxb, nullptr, Wstb, bst, src, y2b, nullptr, DC_, DC_);
  mgemm_k<2,128><<<dim3(8, 32), 256, 0, stream>>>(x1b, y2b, Woutb, bout, nullptr, nullptr, out, DM_, DM_);
}

// Round 20
// 205.620 us; speedup vs baseline: 1.0503x; 1.0503x over previous
//
#include <hip/hip_runtime.h>
#include <hip/hip_bf16.h>
#include <math.h>

#define B_ 2
#define L_ 2048
#define DM_ 1024
#define DC_ 512
#define NH_ 8
#define DH_ 64
#define MR_ (B_*L_)   // 4096 rows
#define BH_ (B_*NH_)  // 16

typedef unsigned short u16;
typedef unsigned int u32;
typedef __attribute__((ext_vector_type(8))) short bf16x8;
typedef __attribute__((ext_vector_type(4))) float f32x4;

static __device__ __forceinline__ u16 f2bf(float x) {
  union { float f; u32 u; } v; v.f = x;
  u32 r = (v.u + 0x7fffu + ((v.u >> 16) & 1u)) >> 16;  // RNE
  return (u16)r;
}
static __device__ __forceinline__ float bf2f(u16 x) {
  union { u32 u; float f; } v; v.u = ((u32)x) << 16;
  return v.f;
}
// fast 2^x (single v_exp_f32); guarded fallback keeps compile safe
static __device__ __forceinline__ float fexp2(float x) {
#if __has_builtin(__builtin_amdgcn_exp2f)
  return __builtin_amdgcn_exp2f(x);
#else
  return __expf(x * 0.69314718056f);
#endif
}
#define LOG2E 1.44269504089f
#define C2    0.18033688011f   /* 0.125 * log2(e) */

// Direct global->LDS DMA, 16B per lane (1KB per wave instruction).
static __device__ __forceinline__ void gld16(const u16* g, u16* l) {
  __builtin_amdgcn_global_load_lds(
      (const __attribute__((address_space(1))) u32*)g,
      (__attribute__((address_space(3))) u32*)l, 16, 0, 0);
}

// ---------------------------------------------------------------------------
// One-shot fp32 -> bf16 conversion: x1, Wq, Wk, Wst, Wout.
// Wqb/Wkb ADJACENT -> used as one stacked [1024][512] matrix.
// ---------------------------------------------------------------------------
__global__ __launch_bounds__(256) void cvt_k(
    const float* __restrict__ src,
    const float* __restrict__ Wq, const float* __restrict__ Wk,
    const float* __restrict__ Wst, const float* __restrict__ Wout,
    u16* __restrict__ x1b, u16* __restrict__ Wqb, u16* __restrict__ Wkb,
    u16* __restrict__ Wstb, u16* __restrict__ Woutb)
{
  int v = blockIdx.x * 256 + threadIdx.x;
  if (v < 524288) {
    const int m = v >> 7, c = (v & 127) << 2;
    float4 f = *(const float4*)(src + (size_t)m * DM_ + c);
    *(ushort4*)(x1b + (size_t)m * DC_ + c) =
        make_ushort4(f2bf(f.x), f2bf(f.y), f2bf(f.z), f2bf(f.w));
    return;
  }
  v -= 524288;
  const float* sp; u16* dp;
  if (v < 65536)       { sp = Wq;   dp = Wqb; }
  else if (v < 131072) { sp = Wk;   dp = Wkb;   v -= 65536; }
  else if (v < 196608) { sp = Wst;  dp = Wstb;  v -= 131072; }
  else                 { sp = Wout; dp = Woutb; v -= 196608; }
  float4 f = *(const float4*)(sp + (size_t)v * 4);
  *(ushort4*)(dp + (size_t)v * 4) =
      make_ushort4(f2bf(f.x), f2bf(f.y), f2bf(f.z), f2bf(f.w));
}

// ---------------------------------------------------------------------------
// MERGED frag + conv kernel (unchanged from r18).
// Blocks 0..511: fragmentize K -> Kf (in place) + Gf.
// Blocks 512..1023: saliency conv1d from bf16 x1b.
// ---------------------------------------------------------------------------
__global__ __launch_bounds__(256) void fc_k(
    const u16* __restrict__ Kh, u16* __restrict__ Kf, u16* __restrict__ Gf,
    const u16* __restrict__ x1b, const float* __restrict__ cw,
    const float* __restrict__ cb, float* __restrict__ sal)
{
  __shared__ float smem[5576];   // conv: xs[10][532]+part[256] ; frag: T (9.2KB)
  const int tid = threadIdx.x;
  if (blockIdx.x < 512) {
    // ---------------- frag part ----------------
    u16* T = (u16*)smem;
    const int bh = blockIdx.x >> 5, mblk = blockIdx.x & 31;
    const int m0 = mblk << 6;
    const u16* Kb = Kh + ((size_t)bh * L_ + m0) * DH_;
    {
      const int r = tid >> 2, c = (tid & 3) << 4;
      *(bf16x8*)&T[r*72 + c]     = *(const bf16x8*)(Kb + (size_t)r * DH_ + c);
      *(bf16x8*)&T[r*72 + c + 8] = *(const bf16x8*)(Kb + (size_t)r * DH_ + c + 8);
    }
    __syncthreads();
#pragma unroll
    for (int i = 0; i < 2; ++i) {
      const int s = tid + (i << 8);
      const int mt_l = s >> 7, ks = (s >> 6) & 1, lane = s & 63;
      const int lr = lane & 15, lg = lane >> 4;
      bf16x8 v = *(bf16x8*)&T[(mt_l*16 + lr)*72 + ks*32 + lg*8];
      *(bf16x8*)(Kf + ((size_t)((bh*128 + mblk*4 + mt_l)*2 + ks)*64 + lane)*8) = v;
    }
#pragma unroll
    for (int i = 0; i < 2; ++i) {
      const int s = tid + (i << 8);
      const int ds = s >> 7, ks = (s >> 6) & 1, lane = s & 63;
      const int lr = lane & 15, lg = lane >> 4;
      bf16x8 v;
#pragma unroll
      for (int j = 0; j < 8; ++j)
        v[j] = (short)T[(ks*32 + lg*8 + j)*72 + ds*16 + lr];
      *(bf16x8*)(Gf + ((size_t)(((bh*4 + ds)*32 + mblk)*2 + ks)*64 + lane)*8) = v;
    }
  } else {
    // ---------------- conv part ----------------
    float* xs = smem;                 // [10][532] flattened
    float* part = smem + 5320;        // [8][8][4]
    const int id = blockIdx.x - 512;
    const int b = id >> 8;
    const int l0 = (id & 255) << 3;
    const int li = tid >> 5;
    const int h  = (tid >> 2) & 7;
    const int cq = tid & 3;
    for (int t = tid; t < 10*128; t += 256) {
      const int r = t >> 7, c4 = (t & 127) << 2;
      const int l = l0 - 1 + r;
      float4 v = make_float4(0.f, 0.f, 0.f, 0.f);
      if (l >= 0 && l < L_) {
        ushort4 u = *(const ushort4*)(x1b + (size_t)(b*L_ + l) * DC_ + c4);
        v = make_float4(bf2f(u.x), bf2f(u.y), bf2f(u.z), bf2f(u.w));
      }
      *(float4*)&xs[r*532 + c4 + (c4 >> 5)] = v;
    }
    __syncthreads();
    float acc = 0.f;
    const int cbase = cq << 7;
#pragma unroll 4
    for (int c = 0; c < 128; ++c) {
      const int cc = cbase + c;
      const int col = cc + (cc >> 5);
      const float* w = cw + ((size_t)h * DC_ + cc) * 3;
      acc += xs[(li+0)*532 + col]*w[0] + xs[(li+1)*532 + col]*w[1]
           + xs[(li+2)*532 + col]*w[2];
    }
    part[(li*8 + h)*4 + cq] = acc;
    __syncthreads();
    if (tid < 64) {
      const int l2 = tid >> 3, h2 = tid & 7;
      const float s = cb[h2] + part[(l2*8 + h2)*4 + 0] + part[(l2*8 + h2)*4 + 1]
                             + part[(l2*8 + h2)*4 + 2] + part[(l2*8 + h2)*4 + 3];
      sal[(size_t)(b*NH_ + h2) * L_ + l0 + l2] = s;
    }
  }
}

// ---------------------------------------------------------------------------
// bf16 MFMA GEMM v2 (r18, gld16 staging — unchanged).
// MODE 0: bf16 heads layout. MODE 1: fused gate -> bf16 [m][n].
// MODE 2: A k-split, fp32 out. MODE 3: fused Q+K (stacked W).
// ---------------------------------------------------------------------------
template<int MODE, int BN>
__global__ __launch_bounds__(256) void mgemm_k(
    const u16* __restrict__ A, const u16* __restrict__ A2,
    const u16* __restrict__ W, const float* __restrict__ bias,
    const float* __restrict__ src, u16* __restrict__ Ob,
    float* __restrict__ Of, int Ndim, int Kdim)
{
  constexpr int MF = (BN == 128) ? 4 : 2;
  constexpr int WC = BN / 64;
  __shared__ u16 As[128 * 32];
  __shared__ u16 Ws[BN * 32];
  const int tid = threadIdx.x;
  const int wid = tid >> 6, lane = tid & 63;
  const int lr = lane & 15, lg = lane >> 4;
  const int wr = wid / WC, wc = wid % WC;
  const int m0 = blockIdx.y << 7;
  const int n0 = blockIdx.x * BN;
  const int lrow = lane >> 2;          // 0..15 (row within 16-row chunk)
  const int lcol = (lane & 3) << 3;    // 0,8,16,24 (u16 col)

  f32x4 acc[MF][4];
#pragma unroll
  for (int mi = 0; mi < MF; ++mi)
#pragma unroll
    for (int ni = 0; ni < 4; ++ni)
      acc[mi][ni] = (f32x4){0.f, 0.f, 0.f, 0.f};

  for (int k0 = 0; k0 < Kdim; k0 += 32) {
    // stage A: 128x32 = 8 chunks of 1KB; wave w does chunks {w, w+4}
#pragma unroll
    for (int c = 0; c < 2; ++c) {
      const int ch = wid + c*4;
      const int row = ch*16 + lrow;
      const u16* ap;
      if (MODE == 2)
        ap = (k0 < 512) ? A  + (size_t)(m0 + row) * 512 + k0 + lcol
                        : A2 + (size_t)(m0 + row) * 512 + (k0 - 512) + lcol;
      else
        ap = A + (size_t)(m0 + row) * Kdim + k0 + lcol;
      gld16(ap, &As[ch*512]);
    }
    // stage W
    if (BN == 128) {
#pragma unroll
      for (int c = 0; c < 2; ++c) {
        const int ch = wid + c*4;
        const int row = ch*16 + lrow;
        gld16(W + (size_t)(n0 + row) * Kdim + k0 + lcol, &Ws[ch*512]);
      }
    } else {
      const int row = wid*16 + lrow;
      gld16(W + (size_t)(n0 + row) * Kdim + k0 + lcol, &Ws[wid*512]);
    }
    __syncthreads();   // drains vmcnt (gld16s complete)
    bf16x8 af[MF], bfr[4];
#pragma unroll
    for (int mi = 0; mi < MF; ++mi)
      af[mi] = *(bf16x8*)&As[(wr * (MF * 16) + mi * 16 + lr) * 32 + lg * 8];
#pragma unroll
    for (int ni = 0; ni < 4; ++ni)
      bfr[ni] = *(bf16x8*)&Ws[(wc * 64 + ni * 16 + lr) * 32 + lg * 8];
#pragma unroll
    for (int mi = 0; mi < MF; ++mi)
#pragma unroll
      for (int ni = 0; ni < 4; ++ni)
        acc[mi][ni] = __builtin_amdgcn_mfma_f32_16x16x32_bf16(
            af[mi], bfr[ni], acc[mi][ni], 0, 0, 0);
    __syncthreads();
  }

#pragma unroll
  for (int mi = 0; mi < MF; ++mi)
#pragma unroll
    for (int ni = 0; ni < 4; ++ni)
#pragma unroll
      for (int r = 0; r < 4; ++r) {
        const int m = m0 + wr * (MF * 16) + mi * 16 + lg * 4 + r;
        const int n = n0 + wc * 64 + ni * 16 + lr;
        if (MODE == 0) {
          const float v = acc[mi][ni][r] + bias[n];
          const int b = m >> 11, l = m & (L_ - 1), h = n >> 6, d = n & (DH_ - 1);
          Ob[((size_t)(b * NH_ + h) * L_ + l) * DH_ + d] = f2bf(v);
        } else if (MODE == 1) {
          const float v = acc[mi][ni][r] + bias[n];
          const float x2 = src[(size_t)m * DM_ + DC_ + n];
          const float s = 1.f / (1.f + __expf(-v));
          Ob[(size_t)m * DC_ + n] = f2bf(s * tanhf(x2) + (1.f - s) * x2);
        } else if (MODE == 2) {
          const float v = acc[mi][ni][r] + bias[n];
          Of[(size_t)m * Ndim + n] = v;
        } else {
          const float bb = (n < 512) ? bias[n] : src[n - 512];
          const float v = acc[mi][ni][r] + bb;
          const int b = m >> 11, l = m & (L_ - 1);
          const int h16 = n >> 6, d = n & (DH_ - 1);
          u16* dst = (h16 < 8) ? Ob : (u16*)Of;
          dst[((size_t)(b * NH_ + (h16 & 7)) * L_ + l) * DH_ + d] = f2bf(v);
        }
      }
}

// ---------------------------------------------------------------------------
// MFMA attention (r18 structure = best measured 202.0) + T5 setprio around
// the MFMA/exp clusters. 4 independent waves, zero barriers after sal
// staging -> the phase-diverse regime where setprio measured +4-7% (m191).
// Swapped QK^T (mfma(K,Q) -> lane-local float4 over m) + PV-linearity split,
// direct f32 stores, exp2 path. 512 blocks, 4 waves x 16 q.
// ---------------------------------------------------------------------------
__global__ __launch_bounds__(256) void attn_k(
    const u16* __restrict__ Qh, const u16* __restrict__ Kf,
    const u16* __restrict__ Gf, const float* __restrict__ sal,
    float* __restrict__ attn, u16* __restrict__ ctxb)
{
  __shared__ u16 Ps[4*16*72];        // [wave][q=16][64+8] bf16
  __shared__ float sal_s[L_];        // pre-scaled by log2e

  const int tid = threadIdx.x;
  const int wid = tid >> 6, lane = tid & 63;
  const int lr = lane & 15, lg = lane >> 4;
  const int lin = blockIdx.x;
  const int swz = (lin & 7) * 64 + (lin >> 3);   // XCD-bijective (512 = 8*64)
  const int bh = swz >> 5, q0 = (swz & 31) << 6;

  const u16* Kfb = Kf + (size_t)bh * 131072;
  const u16* Gfb = Gf + (size_t)bh * 131072;

  {
    const float4* sp = (const float4*)(sal + (size_t)bh * L_);
    float4* dp = (float4*)sal_s;
#pragma unroll
    for (int i = 0; i < 2; ++i) {
      float4 v = sp[tid + i*256];
      v.x *= LOG2E; v.y *= LOG2E; v.z *= LOG2E; v.w *= LOG2E;
      dp[tid + i*256] = v;
    }
  }
  const u16* Qp = Qh + ((size_t)bh * L_ + q0) * DH_;
  bf16x8 qf[2];
  qf[0] = *(const bf16x8*)(Qp + (size_t)(wid*16 + lr) * DH_ + lg*8);
  qf[1] = *(const bf16x8*)(Qp + (size_t)(wid*16 + lr) * DH_ + 32 + lg*8);
  __syncthreads();  // sal_s (only barrier)

  // ============ Sweep A: rowsums + unnormalized PV ============
  float rsum = 0.f;
  f32x4 pvacc[4] = {{0.f,0.f,0.f,0.f},{0.f,0.f,0.f,0.f},
                    {0.f,0.f,0.f,0.f},{0.f,0.f,0.f,0.f}};
  u16* PsW = &Ps[wid*16*72];
  for (int t = 0; t < 32; ++t) {
    const int m0 = t << 6;
    bf16x8 g[8];
#pragma unroll
    for (int f = 0; f < 8; ++f)
      g[f] = *(const bf16x8*)(Gfb + ((size_t)(((f>>1)*32 + t)*2 + (f&1))*64 + lane)*8);
    __builtin_amdgcn_s_setprio(1);
#pragma unroll
    for (int ms = 0; ms < 4; ++ms) {
      bf16x8 k0 = *(const bf16x8*)(Kfb + ((size_t)((t*4 + ms)*2 + 0)*64 + lane)*8);
      bf16x8 k1 = *(const bf16x8*)(Kfb + ((size_t)((t*4 + ms)*2 + 1)*64 + lane)*8);
      f32x4 acc = {0.f, 0.f, 0.f, 0.f};
      acc = __builtin_amdgcn_mfma_f32_16x16x32_bf16(k0, qf[0], acc, 0, 0, 0);
      acc = __builtin_amdgcn_mfma_f32_16x16x32_bf16(k1, qf[1], acc, 0, 0, 0);
      // lane holds: q = lr, m = m0 + ms*16 + lg*4 + r
      float4 sl = *(const float4*)&sal_s[m0 + ms*16 + lg*4];
      float p0 = fexp2(fmaf(acc[0], C2, sl.x));
      float p1 = fexp2(fmaf(acc[1], C2, sl.y));
      float p2 = fexp2(fmaf(acc[2], C2, sl.z));
      float p3 = fexp2(fmaf(acc[3], C2, sl.w));
      rsum += (p0 + p1) + (p2 + p3);
      ushort4 pw = make_ushort4(f2bf(p0), f2bf(p1), f2bf(p2), f2bf(p3));
      *(ushort4*)&PsW[lr*72 + ms*16 + lg*4] = pw;
    }
    // PV: pvacc += P @ K  (A = Ps rows [q][k=m], B = Gf)
#pragma unroll
    for (int ks = 0; ks < 2; ++ks) {
      bf16x8 pa = *(bf16x8*)&PsW[lr*72 + ks*32 + lg*8];
#pragma unroll
      for (int ds = 0; ds < 4; ++ds)
        pvacc[ds] = __builtin_amdgcn_mfma_f32_16x16x32_bf16(pa, g[ds*2+ks], pvacc[ds], 0, 0, 0);
    }
    __builtin_amdgcn_s_setprio(0);
  }
  // rowsum reduce over lg groups: lanes with same lr share q
  rsum += __shfl_xor(rsum, 16);
  rsum += __shfl_xor(rsum, 32);
  const float inv = 1.0f / rsum;     // inv for q = lr, all lanes
  // normalize pvacc rows (pvacc row q = lg*4 + r -> inv from lane lg*4+r)
  float invq[4];
#pragma unroll
  for (int r = 0; r < 4; ++r) invq[r] = __shfl(inv, lg*4 + r);
  // ctx store [b, l, h*64+d] as bf16
  {
    const int b = bh >> 3, h = bh & 7;
#pragma unroll
    for (int ds = 0; ds < 4; ++ds)
#pragma unroll
      for (int r = 0; r < 4; ++r)
        ctxb[((size_t)(b*L_ + q0 + wid*16 + lg*4 + r)) * DC_ + h*DH_ + ds*16 + lr] =
            f2bf(pvacc[ds][r] * invq[r]);
  }

  // ============ Sweep B: normalized attn, direct float4 stores ============
  float* arow = attn + ((size_t)bh * L_ + q0 + wid*16 + lr) * L_;
  for (int t = 0; t < 32; ++t) {
    const int m0 = t << 6;
    __builtin_amdgcn_s_setprio(1);
#pragma unroll
    for (int ms = 0; ms < 4; ++ms) {
      bf16x8 k0 = *(const bf16x8*)(Kfb + ((size_t)((t*4 + ms)*2 + 0)*64 + lane)*8);
      bf16x8 k1 = *(const bf16x8*)(Kfb + ((size_t)((t*4 + ms)*2 + 1)*64 + lane)*8);
      f32x4 acc = {0.f, 0.f, 0.f, 0.f};
      acc = __builtin_amdgcn_mfma_f32_16x16x32_bf16(k0, qf[0], acc, 0, 0, 0);
      acc = __builtin_amdgcn_mfma_f32_16x16x32_bf16(k1, qf[1], acc, 0, 0, 0);
      float4 sl = *(const float4*)&sal_s[m0 + ms*16 + lg*4];
      f32x4 o;
      o[0] = fexp2(fmaf(acc[0], C2, sl.x)) * inv;
      o[1] = fexp2(fmaf(acc[1], C2, sl.y)) * inv;
      o[2] = fexp2(fmaf(acc[2], C2, sl.z)) * inv;
      o[3] = fexp2(fmaf(acc[3], C2, sl.w)) * inv;
      *(f32x4*)(arow + m0 + ms*16 + lg*4) = o;
    }
    __builtin_amdgcn_s_setprio(0);
  }
}

// ---------------------------------------------------------------------------
extern "C" void kernel_launch(void* const* d_in, const int* in_sizes, int n_in,
                              void* d_out, int out_size, void* d_ws, size_t ws_size,
                              hipStream_t stream)
{
  const float* src   = (const float*)d_in[0];
  const float* Wq    = (const float*)d_in[1];
  const float* bq    = (const float*)d_in[2];
  const float* Wk    = (const float*)d_in[3];
  const float* bk    = (const float*)d_in[4];
  const float* convw = (const float*)d_in[5];
  const float* convb = (const float*)d_in[6];
  const float* Wst   = (const float*)d_in[7];
  const float* bst   = (const float*)d_in[8];
  const float* Wout  = (const float*)d_in[9];
  const float* bout  = (const float*)d_in[10];

  float* out  = (float*)d_out;                 // fp32
  float* attn = out + (size_t)MR_ * DM_;

  u16*   x1b   = (u16*)d_ws;                    // [4096][512]
  u16*   Kh    = x1b   + (size_t)MR_ * DC_;     // K heads; becomes Kf in place
  u16*   Qh    = Kh    + (size_t)BH_ * L_ * DH_;
  u16*   Gf    = Qh    + (size_t)BH_ * L_ * DH_;// [16][4][32][2][64][8]
  u16*   ctxb  = Gf    + (size_t)BH_ * L_ * DH_;// [4096][512]
  u16*   y2b   = ctxb  + (size_t)MR_ * DC_;     // [4096][512]
  u16*   Wqb   = y2b   + (size_t)MR_ * DC_;     // [512][512]  (Wqb||Wkb stacked)
  u16*   Wkb   = Wqb   + (size_t)DC_ * DC_;
  u16*   Wstb  = Wkb   + (size_t)DC_ * DC_;
  u16*   Woutb = Wstb  + (size_t)DC_ * DC_;     // [1024][1024]
  float* salb  = (float*)(Woutb + (size_t)DM_ * DM_); // [16][2048]

  (void)in_sizes; (void)n_in; (void)out_size; (void)ws_size;

  cvt_k<<<dim3(3840), 256, 0, stream>>>(src, Wq, Wk, Wst, Wout,
                                        x1b, Wqb, Wkb, Wstb, Woutb);
  // fused Q+K projection: W = [Wqb ; Wkb] stacked, one launch
  mgemm_k<3,64><<<dim3(16, 32), 256, 0, stream>>>(
      x1b, nullptr, Wqb, bq, bk, Qh, (float*)Kh, DM_, DC_);
  // merged: fragmentize K (blocks 0..511) + saliency conv (blocks 512..1023)
  fc_k<<<dim3(1024), 256, 0, stream>>>(Kh, Kh /*in-place Kf*/, Gf,
                                       x1b, convw, convb, salb);
  // fused attention (r18 structure + setprio)
  attn_k<<<dim3(512), 256, 0, stream>>>(Qh, Kh /*Kf*/, Gf, salb, attn, ctxb);
  mgemm_k<1,64><<<dim3(8, 32), 256, 0, stream>>>(ctxb, nullptr, Wstb, bst, src, y2b, nullptr, DC_, DC_);
  mgemm_k<2,128><<<dim3(8, 32), 256, 0, stream>>>(x1b, y2b, Woutb, bout, nullptr, nullptr, out, DM_, DM_);
}

// Round 21
// 201.479 us; speedup vs baseline: 1.0718x; 1.0206x over previous
//
#include <hip/hip_runtime.h>
#include <hip/hip_bf16.h>
#include <math.h>

#define B_ 2
#define L_ 2048
#define DM_ 1024
#define DC_ 512
#define NH_ 8
#define DH_ 64
#define MR_ (B_*L_)   // 4096 rows
#define BH_ (B_*NH_)  // 16

typedef unsigned short u16;
typedef unsigned int u32;
typedef __attribute__((ext_vector_type(8))) short bf16x8;
typedef __attribute__((ext_vector_type(4))) float f32x4;

static __device__ __forceinline__ u16 f2bf(float x) {
  union { float f; u32 u; } v; v.f = x;
  u32 r = (v.u + 0x7fffu + ((v.u >> 16) & 1u)) >> 16;  // RNE
  return (u16)r;
}
static __device__ __forceinline__ float bf2f(u16 x) {
  union { u32 u; float f; } v; v.u = ((u32)x) << 16;
  return v.f;
}
// fast 2^x (single v_exp_f32); guarded fallback keeps compile safe
static __device__ __forceinline__ float fexp2(float x) {
#if __has_builtin(__builtin_amdgcn_exp2f)
  return __builtin_amdgcn_exp2f(x);
#else
  return __expf(x * 0.69314718056f);
#endif
}
#define LOG2E 1.44269504089f
#define C2    0.18033688011f   /* 0.125 * log2(e) */

// Direct global->LDS DMA, 16B per lane (1KB per wave instruction).
static __device__ __forceinline__ void gld16(const u16* g, u16* l) {
  __builtin_amdgcn_global_load_lds(
      (const __attribute__((address_space(1))) u32*)g,
      (__attribute__((address_space(3))) u32*)l, 16, 0, 0);
}

// ---------------------------------------------------------------------------
// One-shot fp32 -> bf16 conversion: x1, Wq, Wk, Wst, Wout.
// Wqb/Wkb ADJACENT -> used as one stacked [1024][512] matrix.
// ---------------------------------------------------------------------------
__global__ __launch_bounds__(256) void cvt_k(
    const float* __restrict__ src,
    const float* __restrict__ Wq, const float* __restrict__ Wk,
    const float* __restrict__ Wst, const float* __restrict__ Wout,
    u16* __restrict__ x1b, u16* __restrict__ Wqb, u16* __restrict__ Wkb,
    u16* __restrict__ Wstb, u16* __restrict__ Woutb)
{
  int v = blockIdx.x * 256 + threadIdx.x;
  if (v < 524288) {
    const int m = v >> 7, c = (v & 127) << 2;
    float4 f = *(const float4*)(src + (size_t)m * DM_ + c);
    *(ushort4*)(x1b + (size_t)m * DC_ + c) =
        make_ushort4(f2bf(f.x), f2bf(f.y), f2bf(f.z), f2bf(f.w));
    return;
  }
  v -= 524288;
  const float* sp; u16* dp;
  if (v < 65536)       { sp = Wq;   dp = Wqb; }
  else if (v < 131072) { sp = Wk;   dp = Wkb;   v -= 65536; }
  else if (v < 196608) { sp = Wst;  dp = Wstb;  v -= 131072; }
  else                 { sp = Wout; dp = Woutb; v -= 196608; }
  float4 f = *(const float4*)(sp + (size_t)v * 4);
  *(ushort4*)(dp + (size_t)v * 4) =
      make_ushort4(f2bf(f.x), f2bf(f.y), f2bf(f.z), f2bf(f.w));
}

// ---------------------------------------------------------------------------
// MERGED frag + conv kernel.
// Blocks 0..511: fragmentize K -> Kf (in place) + Gf.
// Blocks 512..1023: saliency conv1d from bf16 x1b.
// ---------------------------------------------------------------------------
__global__ __launch_bounds__(256) void fc_k(
    const u16* __restrict__ Kh, u16* __restrict__ Kf, u16* __restrict__ Gf,
    const u16* __restrict__ x1b, const float* __restrict__ cw,
    const float* __restrict__ cb, float* __restrict__ sal)
{
  __shared__ float smem[5576];   // conv: xs[10][532]+part[256] ; frag: T (9.2KB)
  const int tid = threadIdx.x;
  if (blockIdx.x < 512) {
    // ---------------- frag part ----------------
    u16* T = (u16*)smem;
    const int bh = blockIdx.x >> 5, mblk = blockIdx.x & 31;
    const int m0 = mblk << 6;
    const u16* Kb = Kh + ((size_t)bh * L_ + m0) * DH_;
    {
      const int r = tid >> 2, c = (tid & 3) << 4;
      *(bf16x8*)&T[r*72 + c]     = *(const bf16x8*)(Kb + (size_t)r * DH_ + c);
      *(bf16x8*)&T[r*72 + c + 8] = *(const bf16x8*)(Kb + (size_t)r * DH_ + c + 8);
    }
    __syncthreads();
#pragma unroll
    for (int i = 0; i < 2; ++i) {
      const int s = tid + (i << 8);
      const int mt_l = s >> 7, ks = (s >> 6) & 1, lane = s & 63;
      const int lr = lane & 15, lg = lane >> 4;
      bf16x8 v = *(bf16x8*)&T[(mt_l*16 + lr)*72 + ks*32 + lg*8];
      *(bf16x8*)(Kf + ((size_t)((bh*128 + mblk*4 + mt_l)*2 + ks)*64 + lane)*8) = v;
    }
#pragma unroll
    for (int i = 0; i < 2; ++i) {
      const int s = tid + (i << 8);
      const int ds = s >> 7, ks = (s >> 6) & 1, lane = s & 63;
      const int lr = lane & 15, lg = lane >> 4;
      bf16x8 v;
#pragma unroll
      for (int j = 0; j < 8; ++j)
        v[j] = (short)T[(ks*32 + lg*8 + j)*72 + ds*16 + lr];
      *(bf16x8*)(Gf + ((size_t)(((bh*4 + ds)*32 + mblk)*2 + ks)*64 + lane)*8) = v;
    }
  } else {
    // ---------------- conv part ----------------
    float* xs = smem;                 // [10][532] flattened
    float* part = smem + 5320;        // [8][8][4]
    const int id = blockIdx.x - 512;
    const int b = id >> 8;
    const int l0 = (id & 255) << 3;
    const int li = tid >> 5;
    const int h  = (tid >> 2) & 7;
    const int cq = tid & 3;
    for (int t = tid; t < 10*128; t += 256) {
      const int r = t >> 7, c4 = (t & 127) << 2;
      const int l = l0 - 1 + r;
      float4 v = make_float4(0.f, 0.f, 0.f, 0.f);
      if (l >= 0 && l < L_) {
        ushort4 u = *(const ushort4*)(x1b + (size_t)(b*L_ + l) * DC_ + c4);
        v = make_float4(bf2f(u.x), bf2f(u.y), bf2f(u.z), bf2f(u.w));
      }
      *(float4*)&xs[r*532 + c4 + (c4 >> 5)] = v;
    }
    __syncthreads();
    float acc = 0.f;
    const int cbase = cq << 7;
#pragma unroll 4
    for (int c = 0; c < 128; ++c) {
      const int cc = cbase + c;
      const int col = cc + (cc >> 5);
      const float* w = cw + ((size_t)h * DC_ + cc) * 3;
      acc += xs[(li+0)*532 + col]*w[0] + xs[(li+1)*532 + col]*w[1]
           + xs[(li+2)*532 + col]*w[2];
    }
    part[(li*8 + h)*4 + cq] = acc;
    __syncthreads();
    if (tid < 64) {
      const int l2 = tid >> 3, h2 = tid & 7;
      const float s = cb[h2] + part[(l2*8 + h2)*4 + 0] + part[(l2*8 + h2)*4 + 1]
                             + part[(l2*8 + h2)*4 + 2] + part[(l2*8 + h2)*4 + 3];
      sal[(size_t)(b*NH_ + h2) * L_ + l0 + l2] = s;
    }
  }
}

// ---------------------------------------------------------------------------
// bf16 MFMA GEMM v2 (gld16 staging).
// MODE 0: bf16 heads layout. MODE 1: fused gate -> bf16 [m][n].
// MODE 2: A k-split, fp32 out. MODE 3: fused Q+K (stacked W).
// ---------------------------------------------------------------------------
template<int MODE, int BN>
__global__ __launch_bounds__(256) void mgemm_k(
    const u16* __restrict__ A, const u16* __restrict__ A2,
    const u16* __restrict__ W, const float* __restrict__ bias,
    const float* __restrict__ src, u16* __restrict__ Ob,
    float* __restrict__ Of, int Ndim, int Kdim)
{
  constexpr int MF = (BN == 128) ? 4 : 2;
  constexpr int WC = BN / 64;
  __shared__ u16 As[128 * 32];
  __shared__ u16 Ws[BN * 32];
  const int tid = threadIdx.x;
  const int wid = tid >> 6, lane = tid & 63;
  const int lr = lane & 15, lg = lane >> 4;
  const int wr = wid / WC, wc = wid % WC;
  const int m0 = blockIdx.y << 7;
  const int n0 = blockIdx.x * BN;
  const int lrow = lane >> 2;          // 0..15 (row within 16-row chunk)
  const int lcol = (lane & 3) << 3;    // 0,8,16,24 (u16 col)

  f32x4 acc[MF][4];
#pragma unroll
  for (int mi = 0; mi < MF; ++mi)
#pragma unroll
    for (int ni = 0; ni < 4; ++ni)
      acc[mi][ni] = (f32x4){0.f, 0.f, 0.f, 0.f};

  for (int k0 = 0; k0 < Kdim; k0 += 32) {
    // stage A: 128x32 = 8 chunks of 1KB; wave w does chunks {w, w+4}
#pragma unroll
    for (int c = 0; c < 2; ++c) {
      const int ch = wid + c*4;
      const int row = ch*16 + lrow;
      const u16* ap;
      if (MODE == 2)
        ap = (k0 < 512) ? A  + (size_t)(m0 + row) * 512 + k0 + lcol
                        : A2 + (size_t)(m0 + row) * 512 + (k0 - 512) + lcol;
      else
        ap = A + (size_t)(m0 + row) * Kdim + k0 + lcol;
      gld16(ap, &As[ch*512]);
    }
    // stage W
    if (BN == 128) {
#pragma unroll
      for (int c = 0; c < 2; ++c) {
        const int ch = wid + c*4;
        const int row = ch*16 + lrow;
        gld16(W + (size_t)(n0 + row) * Kdim + k0 + lcol, &Ws[ch*512]);
      }
    } else {
      const int row = wid*16 + lrow;
      gld16(W + (size_t)(n0 + row) * Kdim + k0 + lcol, &Ws[wid*512]);
    }
    __syncthreads();   // drains vmcnt (gld16s complete)
    bf16x8 af[MF], bfr[4];
#pragma unroll
    for (int mi = 0; mi < MF; ++mi)
      af[mi] = *(bf16x8*)&As[(wr * (MF * 16) + mi * 16 + lr) * 32 + lg * 8];
#pragma unroll
    for (int ni = 0; ni < 4; ++ni)
      bfr[ni] = *(bf16x8*)&Ws[(wc * 64 + ni * 16 + lr) * 32 + lg * 8];
#pragma unroll
    for (int mi = 0; mi < MF; ++mi)
#pragma unroll
      for (int ni = 0; ni < 4; ++ni)
        acc[mi][ni] = __builtin_amdgcn_mfma_f32_16x16x32_bf16(
            af[mi], bfr[ni], acc[mi][ni], 0, 0, 0);
    __syncthreads();
  }

#pragma unroll
  for (int mi = 0; mi < MF; ++mi)
#pragma unroll
    for (int ni = 0; ni < 4; ++ni)
#pragma unroll
      for (int r = 0; r < 4; ++r) {
        const int m = m0 + wr * (MF * 16) + mi * 16 + lg * 4 + r;
        const int n = n0 + wc * 64 + ni * 16 + lr;
        if (MODE == 0) {
          const float v = acc[mi][ni][r] + bias[n];
          const int b = m >> 11, l = m & (L_ - 1), h = n >> 6, d = n & (DH_ - 1);
          Ob[((size_t)(b * NH_ + h) * L_ + l) * DH_ + d] = f2bf(v);
        } else if (MODE == 1) {
          const float v = acc[mi][ni][r] + bias[n];
          const float x2 = src[(size_t)m * DM_ + DC_ + n];
          const float s = 1.f / (1.f + __expf(-v));
          Ob[(size_t)m * DC_ + n] = f2bf(s * tanhf(x2) + (1.f - s) * x2);
        } else if (MODE == 2) {
          const float v = acc[mi][ni][r] + bias[n];
          Of[(size_t)m * Ndim + n] = v;
        } else {
          const float bb = (n < 512) ? bias[n] : src[n - 512];
          const float v = acc[mi][ni][r] + bb;
          const int b = m >> 11, l = m & (L_ - 1);
          const int h16 = n >> 6, d = n & (DH_ - 1);
          u16* dst = (h16 < 8) ? Ob : (u16*)Of;
          dst[((size_t)(b * NH_ + (h16 & 7)) * L_ + l) * DH_ + d] = f2bf(v);
        }
      }
}

// ---------------------------------------------------------------------------
// MFMA attention (r18 structure = best measured 202.0, setprio removed):
// swapped QK^T (mfma(K,Q) -> lane-local float4 over m) + PV-linearity split,
// direct f32 stores, exp2 path. 512 blocks, 4 waves x 16 q, zero barriers
// after sal staging.
// ---------------------------------------------------------------------------
__global__ __launch_bounds__(256) void attn_k(
    const u16* __restrict__ Qh, const u16* __restrict__ Kf,
    const u16* __restrict__ Gf, const float* __restrict__ sal,
    float* __restrict__ attn, u16* __restrict__ ctxb)
{
  __shared__ u16 Ps[4*16*72];        // [wave][q=16][64+8] bf16
  __shared__ float sal_s[L_];        // pre-scaled by log2e

  const int tid = threadIdx.x;
  const int wid = tid >> 6, lane = tid & 63;
  const int lr = lane & 15, lg = lane >> 4;
  const int lin = blockIdx.x;
  const int swz = (lin & 7) * 64 + (lin >> 3);   // XCD-bijective (512 = 8*64)
  const int bh = swz >> 5, q0 = (swz & 31) << 6;

  const u16* Kfb = Kf + (size_t)bh * 131072;
  const u16* Gfb = Gf + (size_t)bh * 131072;

  {
    const float4* sp = (const float4*)(sal + (size_t)bh * L_);
    float4* dp = (float4*)sal_s;
#pragma unroll
    for (int i = 0; i < 2; ++i) {
      float4 v = sp[tid + i*256];
      v.x *= LOG2E; v.y *= LOG2E; v.z *= LOG2E; v.w *= LOG2E;
      dp[tid + i*256] = v;
    }
  }
  const u16* Qp = Qh + ((size_t)bh * L_ + q0) * DH_;
  bf16x8 qf[2];
  qf[0] = *(const bf16x8*)(Qp + (size_t)(wid*16 + lr) * DH_ + lg*8);
  qf[1] = *(const bf16x8*)(Qp + (size_t)(wid*16 + lr) * DH_ + 32 + lg*8);
  __syncthreads();  // sal_s (only barrier)

  // ============ Sweep A: rowsums + unnormalized PV ============
  float rsum = 0.f;
  f32x4 pvacc[4] = {{0.f,0.f,0.f,0.f},{0.f,0.f,0.f,0.f},
                    {0.f,0.f,0.f,0.f},{0.f,0.f,0.f,0.f}};
  u16* PsW = &Ps[wid*16*72];
  for (int t = 0; t < 32; ++t) {
    const int m0 = t << 6;
    bf16x8 g[8];
#pragma unroll
    for (int f = 0; f < 8; ++f)
      g[f] = *(const bf16x8*)(Gfb + ((size_t)(((f>>1)*32 + t)*2 + (f&1))*64 + lane)*8);
#pragma unroll
    for (int ms = 0; ms < 4; ++ms) {
      bf16x8 k0 = *(const bf16x8*)(Kfb + ((size_t)((t*4 + ms)*2 + 0)*64 + lane)*8);
      bf16x8 k1 = *(const bf16x8*)(Kfb + ((size_t)((t*4 + ms)*2 + 1)*64 + lane)*8);
      f32x4 acc = {0.f, 0.f, 0.f, 0.f};
      acc = __builtin_amdgcn_mfma_f32_16x16x32_bf16(k0, qf[0], acc, 0, 0, 0);
      acc = __builtin_amdgcn_mfma_f32_16x16x32_bf16(k1, qf[1], acc, 0, 0, 0);
      // lane holds: q = lr, m = m0 + ms*16 + lg*4 + r
      float4 sl = *(const float4*)&sal_s[m0 + ms*16 + lg*4];
      float p0 = fexp2(fmaf(acc[0], C2, sl.x));
      float p1 = fexp2(fmaf(acc[1], C2, sl.y));
      float p2 = fexp2(fmaf(acc[2], C2, sl.z));
      float p3 = fexp2(fmaf(acc[3], C2, sl.w));
      rsum += (p0 + p1) + (p2 + p3);
      ushort4 pw = make_ushort4(f2bf(p0), f2bf(p1), f2bf(p2), f2bf(p3));
      *(ushort4*)&PsW[lr*72 + ms*16 + lg*4] = pw;
    }
    // PV: pvacc += P @ K  (A = Ps rows [q][k=m], B = Gf)
#pragma unroll
    for (int ks = 0; ks < 2; ++ks) {
      bf16x8 pa = *(bf16x8*)&PsW[lr*72 + ks*32 + lg*8];
#pragma unroll
      for (int ds = 0; ds < 4; ++ds)
        pvacc[ds] = __builtin_amdgcn_mfma_f32_16x16x32_bf16(pa, g[ds*2+ks], pvacc[ds], 0, 0, 0);
    }
  }
  // rowsum reduce over lg groups: lanes with same lr share q
  rsum += __shfl_xor(rsum, 16);
  rsum += __shfl_xor(rsum, 32);
  const float inv = 1.0f / rsum;     // inv for q = lr, all lanes
  // normalize pvacc rows (pvacc row q = lg*4 + r -> inv from lane lg*4+r)
  float invq[4];
#pragma unroll
  for (int r = 0; r < 4; ++r) invq[r] = __shfl(inv, lg*4 + r);
  // ctx store [b, l, h*64+d] as bf16
  {
    const int b = bh >> 3, h = bh & 7;
#pragma unroll
    for (int ds = 0; ds < 4; ++ds)
#pragma unroll
      for (int r = 0; r < 4; ++r)
        ctxb[((size_t)(b*L_ + q0 + wid*16 + lg*4 + r)) * DC_ + h*DH_ + ds*16 + lr] =
            f2bf(pvacc[ds][r] * invq[r]);
  }

  // ============ Sweep B: normalized attn, direct float4 stores ============
  float* arow = attn + ((size_t)bh * L_ + q0 + wid*16 + lr) * L_;
  for (int t = 0; t < 32; ++t) {
    const int m0 = t << 6;
#pragma unroll
    for (int ms = 0; ms < 4; ++ms) {
      bf16x8 k0 = *(const bf16x8*)(Kfb + ((size_t)((t*4 + ms)*2 + 0)*64 + lane)*8);
      bf16x8 k1 = *(const bf16x8*)(Kfb + ((size_t)((t*4 + ms)*2 + 1)*64 + lane)*8);
      f32x4 acc = {0.f, 0.f, 0.f, 0.f};
      acc = __builtin_amdgcn_mfma_f32_16x16x32_bf16(k0, qf[0], acc, 0, 0, 0);
      acc = __builtin_amdgcn_mfma_f32_16x16x32_bf16(k1, qf[1], acc, 0, 0, 0);
      float4 sl = *(const float4*)&sal_s[m0 + ms*16 + lg*4];
      f32x4 o;
      o[0] = fexp2(fmaf(acc[0], C2, sl.x)) * inv;
      o[1] = fexp2(fmaf(acc[1], C2, sl.y)) * inv;
      o[2] = fexp2(fmaf(acc[2], C2, sl.z)) * inv;
      o[3] = fexp2(fmaf(acc[3], C2, sl.w)) * inv;
      *(f32x4*)(arow + m0 + ms*16 + lg*4) = o;
    }
  }
}

// ---------------------------------------------------------------------------
extern "C" void kernel_launch(void* const* d_in, const int* in_sizes, int n_in,
                              void* d_out, int out_size, void* d_ws, size_t ws_size,
                              hipStream_t stream)
{
  const float* src   = (const float*)d_in[0];
  const float* Wq    = (const float*)d_in[1];
  const float* bq    = (const float*)d_in[2];
  const float* Wk    = (const float*)d_in[3];
  const float* bk    = (const float*)d_in[4];
  const float* convw = (const float*)d_in[5];
  const float* convb = (const float*)d_in[6];
  const float* Wst   = (const float*)d_in[7];
  const float* bst   = (const float*)d_in[8];
  const float* Wout  = (const float*)d_in[9];
  const float* bout  = (const float*)d_in[10];

  float* out  = (float*)d_out;                 // fp32
  float* attn = out + (size_t)MR_ * DM_;

  u16*   x1b   = (u16*)d_ws;                    // [4096][512]
  u16*   Kh    = x1b   + (size_t)MR_ * DC_;     // K heads; becomes Kf in place
  u16*   Qh    = Kh    + (size_t)BH_ * L_ * DH_;
  u16*   Gf    = Qh    + (size_t)BH_ * L_ * DH_;// [16][4][32][2][64][8]
  u16*   ctxb  = Gf    + (size_t)BH_ * L_ * DH_;// [4096][512]
  u16*   y2b   = ctxb  + (size_t)MR_ * DC_;     // [4096][512]
  u16*   Wqb   = y2b   + (size_t)MR_ * DC_;     // [512][512]  (Wqb||Wkb stacked)
  u16*   Wkb   = Wqb   + (size_t)DC_ * DC_;
  u16*   Wstb  = Wkb   + (size_t)DC_ * DC_;
  u16*   Woutb = Wstb  + (size_t)DC_ * DC_;     // [1024][1024]
  float* salb  = (float*)(Woutb + (size_t)DM_ * DM_); // [16][2048]

  (void)in_sizes; (void)n_in; (void)out_size; (void)ws_size;

  cvt_k<<<dim3(3840), 256, 0, stream>>>(src, Wq, Wk, Wst, Wout,
                                        x1b, Wqb, Wkb, Wstb, Woutb);
  // fused Q+K projection: W = [Wqb ; Wkb] stacked, one launch
  mgemm_k<3,64><<<dim3(16, 32), 256, 0, stream>>>(
      x1b, nullptr, Wqb, bq, bk, Qh, (float*)Kh, DM_, DC_);
  // merged: fragmentize K (blocks 0..511) + saliency conv (blocks 512..1023)
  fc_k<<<dim3(1024), 256, 0, stream>>>(Kh, Kh /*in-place Kf*/, Gf,
                                       x1b, convw, convb, salb);
  // fused attention (r18 structure, best measured)
  attn_k<<<dim3(512), 256, 0, stream>>>(Qh, Kh /*Kf*/, Gf, salb, attn, ctxb);
  mgemm_k<1,64><<<dim3(8, 32), 256, 0, stream>>>(ctxb, nullptr, Wstb, bst, src, y2b, nullptr, DC_, DC_);
  mgemm_k<2,128><<<dim3(8, 32), 256, 0, stream>>>(x1b, y2b, Woutb, bout, nullptr, nullptr, out, DM_, DM_);
}